// Round 2
// baseline (474.945 us; speedup 1.0000x reference)
//
#include <hip/hip_runtime.h>
#include <math.h>

#define N    5000
#define E    4
#define H    64
#define PV   300
#define RD   64
#define NS_  8
#define SP_  6
#define NI   (RD + NS_ + SP_)   // 78
#define GH   (2 * H)            // 128
#define MSGW (2 * E * H)        // 512
#define CAP  128

__device__ __forceinline__ float wsum(float v) {
    v += __shfl_xor(v, 32, 64);
    v += __shfl_xor(v, 16, 64);
    v += __shfl_xor(v, 8, 64);
    v += __shfl_xor(v, 4, 64);
    v += __shfl_xor(v, 2, 64);
    v += __shfl_xor(v, 1, 64);
    return v;
}

// ---------------------------------------------------------------------------
// Kz: zero the count arrays (replaces pathologically slow in-graph memset node)
// 2*E*N ints = 40000 ints = 10000 int4
// ---------------------------------------------------------------------------
__global__ __launch_bounds__(256) void k_zero(int4* __restrict__ p) {
    const int i = blockIdx.x * 256 + threadIdx.x;
    if (i < (2 * E * N) / 4) p[i] = make_int4(0, 0, 0, 0);
}

// ---------------------------------------------------------------------------
// K0: h0 = tanh(concat[tanh(nv@W_red+b_red), node_states, node_sp] @ W_init + b_init)
// 4 nodes per 64-thread block.
// ---------------------------------------------------------------------------
__global__ __launch_bounds__(64) void k_init(
    const float* __restrict__ NV, const float* __restrict__ NSt,
    const float* __restrict__ SPos, const float* __restrict__ Wred,
    const float* __restrict__ bred, const float* __restrict__ Winit,
    const float* __restrict__ binit, float* __restrict__ h)
{
    __shared__ float nv[4 * PV];
    __shared__ float ni[4 * NI];
    const int n0 = blockIdx.x * 4;
    const int j = threadIdx.x;

    for (int idx = j; idx < 4 * PV; idx += 64) nv[idx] = NV[(size_t)n0 * PV + idx];
    __syncthreads();

    float acc[4];
    {
        const float br = bred[j];
        #pragma unroll
        for (int nn = 0; nn < 4; ++nn) acc[nn] = br;
    }
    for (int k = 0; k < PV; ++k) {
        const float w = Wred[k * RD + j];
        #pragma unroll
        for (int nn = 0; nn < 4; ++nn) acc[nn] += nv[nn * PV + k] * w;
    }
    #pragma unroll
    for (int nn = 0; nn < 4; ++nn) ni[nn * NI + j] = tanhf(acc[nn]);
    if (j < NS_) {
        #pragma unroll
        for (int nn = 0; nn < 4; ++nn) ni[nn * NI + RD + j] = NSt[(size_t)(n0 + nn) * NS_ + j];
    }
    if (j < SP_) {
        #pragma unroll
        for (int nn = 0; nn < 4; ++nn) ni[nn * NI + RD + NS_ + j] = SPos[(size_t)(n0 + nn) * SP_ + j];
    }
    __syncthreads();

    float a2[4];
    {
        const float bi = binit[j];
        #pragma unroll
        for (int nn = 0; nn < 4; ++nn) a2[nn] = bi;
    }
    for (int k = 0; k < NI; ++k) {
        const float w = Winit[k * H + j];
        #pragma unroll
        for (int nn = 0; nn < 4; ++nn) a2[nn] += ni[nn * NI + k] * w;
    }
    #pragma unroll
    for (int nn = 0; nn < 4; ++nn) h[(size_t)(n0 + nn) * H + j] = tanhf(a2[nn]);
}

// ---------------------------------------------------------------------------
// K1: build out/in adjacency lists from dense 0/1 fp32 A. One block per (e,row).
// ---------------------------------------------------------------------------
__global__ __launch_bounds__(256) void k_build(
    const float* __restrict__ A, int* __restrict__ cnt_out, int* __restrict__ cnt_in,
    unsigned short* __restrict__ idx_out, unsigned short* __restrict__ idx_in)
{
    const int r = blockIdx.x;          // e*N + n
    const int e = r / N;
    const int n = r - e * N;
    __shared__ int s_cnt;
    __shared__ int s_cols[CAP];
    if (threadIdx.x == 0) s_cnt = 0;
    __syncthreads();

    const float4* row = (const float4*)(A + (size_t)r * N);
    for (int c = threadIdx.x; c < N / 4; c += 256) {
        const float4 v = row[c];
        if (v.x != 0.f) { int p = atomicAdd(&s_cnt, 1); if (p < CAP) s_cols[p] = 4 * c + 0; }
        if (v.y != 0.f) { int p = atomicAdd(&s_cnt, 1); if (p < CAP) s_cols[p] = 4 * c + 1; }
        if (v.z != 0.f) { int p = atomicAdd(&s_cnt, 1); if (p < CAP) s_cols[p] = 4 * c + 2; }
        if (v.w != 0.f) { int p = atomicAdd(&s_cnt, 1); if (p < CAP) s_cols[p] = 4 * c + 3; }
    }
    __syncthreads();
    const int cnt = min(s_cnt, CAP);
    if (threadIdx.x == 0) cnt_out[r] = cnt;
    for (int i = threadIdx.x; i < cnt; i += 256)
        idx_out[(size_t)r * CAP + i] = (unsigned short)s_cols[i];
    for (int i = threadIdx.x; i < cnt; i += 256) {
        const int m = s_cols[i];
        const int p = atomicAdd(&cnt_in[e * N + m], 1);
        if (p < CAP) idx_in[(size_t)(e * N + m) * CAP + p] = (unsigned short)n;
    }
}

// ---------------------------------------------------------------------------
// K2: hs_out/hs_in = tanh(h @ W_out/W_in + b). 8 nodes per 256-thread block.
// ---------------------------------------------------------------------------
__global__ __launch_bounds__(256) void k_hs(
    const float* __restrict__ h, const float* __restrict__ Wout,
    const float* __restrict__ bout, const float* __restrict__ Win,
    const float* __restrict__ bin, float* __restrict__ hs_out,
    float* __restrict__ hs_in)
{
    __shared__ float hsd[8 * H];
    const int n0 = blockIdx.x * 8;
    const int tid = threadIdx.x;
    const int e = tid >> 6, j = tid & 63;

    for (int idx = tid; idx < 8 * H; idx += 256) hsd[idx] = h[(size_t)n0 * H + idx];
    __syncthreads();

    float aO[8], aI[8];
    {
        const float bO = bout[e * H + j], bI = bin[e * H + j];
        #pragma unroll
        for (int nn = 0; nn < 8; ++nn) { aO[nn] = bO; aI[nn] = bI; }
    }
    for (int k = 0; k < H; ++k) {
        const float wo = Wout[(e * H + k) * H + j];
        const float wi = Win[(e * H + k) * H + j];
        #pragma unroll
        for (int nn = 0; nn < 8; ++nn) {
            const float hv = hsd[nn * H + k];
            aO[nn] += hv * wo;
            aI[nn] += hv * wi;
        }
    }
    #pragma unroll
    for (int nn = 0; nn < 8; ++nn) {
        hs_out[((size_t)e * N + n0 + nn) * H + j] = tanhf(aO[nn]);
        hs_in[((size_t)e * N + n0 + nn) * H + j]  = tanhf(aI[nn]);
    }
}

// ---------------------------------------------------------------------------
// K3: sparse message aggregation. One block per node, 8 waves: (dir,e) per wave.
// ---------------------------------------------------------------------------
__global__ __launch_bounds__(512) void k_msg(
    const float* __restrict__ hs_out, const float* __restrict__ hs_in,
    const int* __restrict__ cnt_out, const int* __restrict__ cnt_in,
    const unsigned short* __restrict__ idx_out, const unsigned short* __restrict__ idx_in,
    float* __restrict__ msg)
{
    const int n = blockIdx.x;
    const int tid = threadIdx.x;
    const int dir = tid >> 8;            // 0=out, 1=in
    const int e = (tid >> 6) & 3, j = tid & 63;

    const float* hs = dir ? hs_in : hs_out;
    const int* cnt = dir ? cnt_in : cnt_out;
    const unsigned short* idx = dir ? idx_in : idx_out;

    const int r = e * N + n;
    const int c = min(cnt[r], CAP);
    const unsigned short* lst = idx + (size_t)r * CAP;
    const float* base = hs + (size_t)e * N * H + j;

    float acc = 0.f;
    int i = 0;
    for (; i + 4 <= c; i += 4) {
        const int m0 = lst[i], m1 = lst[i + 1], m2 = lst[i + 2], m3 = lst[i + 3];
        acc += base[(size_t)m0 * H];
        acc += base[(size_t)m1 * H];
        acc += base[(size_t)m2 * H];
        acc += base[(size_t)m3 * H];
    }
    for (; i < c; ++i) acc += base[(size_t)lst[i] * H];

    msg[(size_t)n * MSGW + dir * (E * H) + e * H + j] = acc;
}

// ---------------------------------------------------------------------------
// K4: fused GRU + 4 LayerNorms. 8 nodes per 256-thread block (2 nodes/wave).
// ---------------------------------------------------------------------------
__global__ __launch_bounds__(256) void k_gru(
    const float* __restrict__ msg, const float* __restrict__ h,
    const float* __restrict__ Wih_rz, const float* __restrict__ bih_rz,
    const float* __restrict__ Whh_rz, const float* __restrict__ bhh_rz,
    const float* __restrict__ Wih_c, const float* __restrict__ bih_c,
    const float* __restrict__ Whh_c, const float* __restrict__ bhh_c,
    const float* __restrict__ g_i2h, const float* __restrict__ be_i2h,
    const float* __restrict__ g_h2h, const float* __restrict__ be_h2h,
    const float* __restrict__ g_ci, const float* __restrict__ be_ci,
    const float* __restrict__ g_ch, const float* __restrict__ be_ch,
    float* __restrict__ h_out)
{
    __shared__ float ms[8 * MSGW];   // 16 KB
    __shared__ float hsd[8 * H];     // 2 KB
    const int n0 = blockIdx.x * 8;
    const int tid = threadIdx.x;
    const int j = tid & 63;
    const int wv = tid >> 6;         // 0..3
    const int nn0 = wv * 2;          // this wave owns nodes nn0, nn0+1

    {   // stage msg + h
        const float4* msrc = (const float4*)(msg + (size_t)n0 * MSGW);
        float4* mdst = (float4*)ms;
        for (int idx = tid; idx < 8 * MSGW / 4; idx += 256) mdst[idx] = msrc[idx];
        const float4* hsrc = (const float4*)(h + (size_t)n0 * H);
        float4* hdst = (float4*)hsd;
        for (int idx = tid; idx < 8 * H / 4; idx += 256) hdst[idx] = hsrc[idx];
    }
    __syncthreads();

    // x_rz = msg @ W_ih_rz + b   (thread j holds cols j, j+64, 2 nodes)
    float a0[2], a1[2], b0[2], b1[2];
    {
        const float v0 = bih_rz[j], v1 = bih_rz[H + j];
        #pragma unroll
        for (int nn = 0; nn < 2; ++nn) { a0[nn] = v0; a1[nn] = v1; }
    }
    for (int k = 0; k < MSGW; ++k) {
        const float w0 = Wih_rz[k * GH + j];
        const float w1 = Wih_rz[k * GH + H + j];
        #pragma unroll
        for (int nn = 0; nn < 2; ++nn) {
            const float mv = ms[(nn0 + nn) * MSGW + k];
            a0[nn] += mv * w0;
            a1[nn] += mv * w1;
        }
    }
    {
        const float v0 = bhh_rz[j], v1 = bhh_rz[H + j];
        #pragma unroll
        for (int nn = 0; nn < 2; ++nn) { b0[nn] = v0; b1[nn] = v1; }
    }
    for (int k = 0; k < H; ++k) {
        const float w0 = Whh_rz[k * GH + j];
        const float w1 = Whh_rz[k * GH + H + j];
        #pragma unroll
        for (int nn = 0; nn < 2; ++nn) {
            const float hv = hsd[(nn0 + nn) * H + k];
            b0[nn] += hv * w0;
            b1[nn] += hv * w1;
        }
    }

    const float gi0 = g_i2h[j], gi1 = g_i2h[H + j], bi0 = be_i2h[j], bi1 = be_i2h[H + j];
    const float gh0 = g_h2h[j], gh1 = g_h2h[H + j], bh0 = be_h2h[j], bh1 = be_h2h[H + j];
    float r_[2], z_[2];
    #pragma unroll
    for (int nn = 0; nn < 2; ++nn) {
        float s  = wsum(a0[nn] + a1[nn]);
        float q  = wsum(a0[nn] * a0[nn] + a1[nn] * a1[nn]);
        float mn = s * (1.f / GH);
        float vr = q * (1.f / GH) - mn * mn;
        float rs = rsqrtf(vr + 1e-5f);
        float x0 = (a0[nn] - mn) * rs * gi0 + bi0;
        float x1 = (a1[nn] - mn) * rs * gi1 + bi1;
        float s2  = wsum(b0[nn] + b1[nn]);
        float q2  = wsum(b0[nn] * b0[nn] + b1[nn] * b1[nn]);
        float mn2 = s2 * (1.f / GH);
        float vr2 = q2 * (1.f / GH) - mn2 * mn2;
        float rs2 = rsqrtf(vr2 + 1e-5f);
        float y0 = (b0[nn] - mn2) * rs2 * gh0 + bh0;
        float y1 = (b1[nn] - mn2) * rs2 * gh1 + bh1;
        r_[nn] = 1.f / (1.f + expf(-(x0 + y0)));
        z_[nn] = 1.f / (1.f + expf(-(x1 + y1)));
    }

    // x_c = msg @ W_ih_c, hn_c = h @ W_hh_c
    float c0[2], ch[2];
    {
        const float v = bih_c[j];
        #pragma unroll
        for (int nn = 0; nn < 2; ++nn) c0[nn] = v;
    }
    for (int k = 0; k < MSGW; ++k) {
        const float w = Wih_c[k * H + j];
        #pragma unroll
        for (int nn = 0; nn < 2; ++nn) c0[nn] += ms[(nn0 + nn) * MSGW + k] * w;
    }
    {
        const float v = bhh_c[j];
        #pragma unroll
        for (int nn = 0; nn < 2; ++nn) ch[nn] = v;
    }
    for (int k = 0; k < H; ++k) {
        const float w = Whh_c[k * H + j];
        #pragma unroll
        for (int nn = 0; nn < 2; ++nn) ch[nn] += hsd[(nn0 + nn) * H + k] * w;
    }

    const float gci = g_ci[j], bci = be_ci[j], gchv = g_ch[j], bchv = be_ch[j];
    #pragma unroll
    for (int nn = 0; nn < 2; ++nn) {
        float s  = wsum(c0[nn]);
        float q  = wsum(c0[nn] * c0[nn]);
        float mn = s * (1.f / H);
        float vr = q * (1.f / H) - mn * mn;
        float rs = rsqrtf(vr + 1e-5f);
        float xc = (c0[nn] - mn) * rs * gci + bci;
        float s2  = wsum(ch[nn]);
        float q2  = wsum(ch[nn] * ch[nn]);
        float mn2 = s2 * (1.f / H);
        float vr2 = q2 * (1.f / H) - mn2 * mn2;
        float rs2 = rsqrtf(vr2 + 1e-5f);
        float hc = (ch[nn] - mn2) * rs2 * gchv + bchv;
        float c  = tanhf(xc + r_[nn] * hc);
        const float hp = hsd[(nn0 + nn) * H + j];
        h_out[(size_t)(n0 + nn0 + nn) * H + j] = z_[nn] * hp + (1.f - z_[nn]) * c;
    }
}

// ---------------------------------------------------------------------------
extern "C" void kernel_launch(void* const* d_in, const int* in_sizes, int n_in,
                              void* d_out, int out_size, void* d_ws, size_t ws_size,
                              hipStream_t stream)
{
    const float* A      = (const float*)d_in[0];
    const float* nstate = (const float*)d_in[1];
    // d_in[2] node_ids unused
    const float* nvec   = (const float*)d_in[3];
    const float* nsp    = (const float*)d_in[4];
    const float* Wred   = (const float*)d_in[5];
    const float* bred   = (const float*)d_in[6];
    const float* Winit  = (const float*)d_in[7];
    const float* binit  = (const float*)d_in[8];
    const float* Wout   = (const float*)d_in[9];
    const float* bout   = (const float*)d_in[10];
    const float* Wine   = (const float*)d_in[11];
    const float* bine   = (const float*)d_in[12];
    const float* Wih_rz = (const float*)d_in[13];
    const float* bih_rz = (const float*)d_in[14];
    const float* Whh_rz = (const float*)d_in[15];
    const float* bhh_rz = (const float*)d_in[16];
    const float* Wih_c  = (const float*)d_in[17];
    const float* bih_c  = (const float*)d_in[18];
    const float* Whh_c  = (const float*)d_in[19];
    const float* bhh_c  = (const float*)d_in[20];
    const float* g_i2h  = (const float*)d_in[21];
    const float* be_i2h = (const float*)d_in[22];
    const float* g_h2h  = (const float*)d_in[23];
    const float* be_h2h = (const float*)d_in[24];
    const float* g_ci   = (const float*)d_in[25];
    const float* be_ci  = (const float*)d_in[26];
    const float* g_ch   = (const float*)d_in[27];
    const float* be_ch  = (const float*)d_in[28];

    char* ws = (char*)d_ws;
    size_t off = 0;
    auto alloc = [&](size_t bytes) {
        void* p = ws + off;
        off += (bytes + 255) & ~(size_t)255;
        return p;
    };
    float* h0  = (float*)alloc((size_t)N * H * 4);
    float* h1  = (float*)alloc((size_t)N * H * 4);
    float* hsO = (float*)alloc((size_t)E * N * H * 4);
    float* hsI = (float*)alloc((size_t)E * N * H * 4);
    float* msg = (float*)alloc((size_t)N * MSGW * 4);
    int* cnts  = (int*)alloc((size_t)2 * E * N * 4);
    int* cnt_out = cnts;
    int* cnt_in  = cnts + E * N;
    unsigned short* idxO = (unsigned short*)alloc((size_t)E * N * CAP * 2);
    unsigned short* idxI = (unsigned short*)alloc((size_t)E * N * CAP * 2);

    k_zero<<<(2 * E * N / 4 + 255) / 256, 256, 0, stream>>>((int4*)cnts);
    k_init<<<N / 4, 64, 0, stream>>>(nvec, nstate, nsp, Wred, bred, Winit, binit, h0);
    k_build<<<E * N, 256, 0, stream>>>(A, cnt_out, cnt_in, idxO, idxI);

    const float* hc = h0;
    for (int t = 0; t < 2; ++t) {
        k_hs<<<N / 8, 256, 0, stream>>>(hc, Wout, bout, Wine, bine, hsO, hsI);
        k_msg<<<N, 512, 0, stream>>>(hsO, hsI, cnt_out, cnt_in, idxO, idxI, msg);
        float* hn = (t == 1) ? (float*)d_out : h1;
        k_gru<<<N / 8, 256, 0, stream>>>(msg, hc, Wih_rz, bih_rz, Whh_rz, bhh_rz,
                                         Wih_c, bih_c, Whh_c, bhh_c,
                                         g_i2h, be_i2h, g_h2h, be_h2h,
                                         g_ci, be_ci, g_ch, be_ch, hn);
        hc = hn;
    }
}

// Round 3
// 450.133 us; speedup vs baseline: 1.0551x; 1.0551x over previous
//
#include <hip/hip_runtime.h>
#include <math.h>

#define N    5000
#define E    4
#define H    64
#define PV   300
#define RD   64
#define NS_  8
#define SP_  6
#define NI   (RD + NS_ + SP_)   // 78
#define GH   (2 * H)            // 128
#define MSGW (2 * E * H)        // 512
#define CAP  128

__device__ __forceinline__ float wsum(float v) {
    v += __shfl_xor(v, 32, 64);
    v += __shfl_xor(v, 16, 64);
    v += __shfl_xor(v, 8, 64);
    v += __shfl_xor(v, 4, 64);
    v += __shfl_xor(v, 2, 64);
    v += __shfl_xor(v, 1, 64);
    return v;
}

// ---------------------------------------------------------------------------
// Kz: zero the count arrays
// ---------------------------------------------------------------------------
__global__ __launch_bounds__(256) void k_zero(int4* __restrict__ p) {
    const int i = blockIdx.x * 256 + threadIdx.x;
    if (i < (2 * E * N) / 4) p[i] = make_int4(0, 0, 0, 0);
}

// ---------------------------------------------------------------------------
// K0: h0 = tanh(concat[tanh(nv@W_red+b_red), node_states, node_sp] @ W_init + b_init)
// ---------------------------------------------------------------------------
__global__ __launch_bounds__(64) void k_init(
    const float* __restrict__ NV, const float* __restrict__ NSt,
    const float* __restrict__ SPos, const float* __restrict__ Wred,
    const float* __restrict__ bred, const float* __restrict__ Winit,
    const float* __restrict__ binit, float* __restrict__ h)
{
    __shared__ float nv[4 * PV];
    __shared__ float ni[4 * NI];
    const int n0 = blockIdx.x * 4;
    const int j = threadIdx.x;

    for (int idx = j; idx < 4 * PV; idx += 64) nv[idx] = NV[(size_t)n0 * PV + idx];
    __syncthreads();

    float acc[4];
    {
        const float br = bred[j];
        #pragma unroll
        for (int nn = 0; nn < 4; ++nn) acc[nn] = br;
    }
    for (int k = 0; k < PV; ++k) {
        const float w = Wred[k * RD + j];
        #pragma unroll
        for (int nn = 0; nn < 4; ++nn) acc[nn] += nv[nn * PV + k] * w;
    }
    #pragma unroll
    for (int nn = 0; nn < 4; ++nn) ni[nn * NI + j] = tanhf(acc[nn]);
    if (j < NS_) {
        #pragma unroll
        for (int nn = 0; nn < 4; ++nn) ni[nn * NI + RD + j] = NSt[(size_t)(n0 + nn) * NS_ + j];
    }
    if (j < SP_) {
        #pragma unroll
        for (int nn = 0; nn < 4; ++nn) ni[nn * NI + RD + NS_ + j] = SPos[(size_t)(n0 + nn) * SP_ + j];
    }
    __syncthreads();

    float a2[4];
    {
        const float bi = binit[j];
        #pragma unroll
        for (int nn = 0; nn < 4; ++nn) a2[nn] = bi;
    }
    for (int k = 0; k < NI; ++k) {
        const float w = Winit[k * H + j];
        #pragma unroll
        for (int nn = 0; nn < 4; ++nn) a2[nn] += ni[nn * NI + k] * w;
    }
    #pragma unroll
    for (int nn = 0; nn < 4; ++nn) h[(size_t)(n0 + nn) * H + j] = tanhf(a2[nn]);
}

// ---------------------------------------------------------------------------
// K1: build out/in adjacency lists from dense 0/1 fp32 A. One block per (e,row).
// ---------------------------------------------------------------------------
__global__ __launch_bounds__(256) void k_build(
    const float* __restrict__ A, int* __restrict__ cnt_out, int* __restrict__ cnt_in,
    unsigned short* __restrict__ idx_out, unsigned short* __restrict__ idx_in)
{
    const int r = blockIdx.x;          // e*N + n
    const int e = r / N;
    const int n = r - e * N;
    __shared__ int s_cnt;
    __shared__ int s_cols[CAP];
    if (threadIdx.x == 0) s_cnt = 0;
    __syncthreads();

    const float4* row = (const float4*)(A + (size_t)r * N);
    for (int c = threadIdx.x; c < N / 4; c += 256) {
        const float4 v = row[c];
        if (v.x != 0.f) { int p = atomicAdd(&s_cnt, 1); if (p < CAP) s_cols[p] = 4 * c + 0; }
        if (v.y != 0.f) { int p = atomicAdd(&s_cnt, 1); if (p < CAP) s_cols[p] = 4 * c + 1; }
        if (v.z != 0.f) { int p = atomicAdd(&s_cnt, 1); if (p < CAP) s_cols[p] = 4 * c + 2; }
        if (v.w != 0.f) { int p = atomicAdd(&s_cnt, 1); if (p < CAP) s_cols[p] = 4 * c + 3; }
    }
    __syncthreads();
    const int cnt = min(s_cnt, CAP);
    if (threadIdx.x == 0) cnt_out[r] = cnt;
    for (int i = threadIdx.x; i < cnt; i += 256)
        idx_out[(size_t)r * CAP + i] = (unsigned short)s_cols[i];
    for (int i = threadIdx.x; i < cnt; i += 256) {
        const int m = s_cols[i];
        const int p = atomicAdd(&cnt_in[e * N + m], 1);
        if (p < CAP) idx_in[(size_t)(e * N + m) * CAP + p] = (unsigned short)n;
    }
}

// ---------------------------------------------------------------------------
// K2: hs_out/hs_in = tanh(h @ W_out/W_in + b). 8 nodes per 256-thread block.
// ---------------------------------------------------------------------------
__global__ __launch_bounds__(256) void k_hs(
    const float* __restrict__ h, const float* __restrict__ Wout,
    const float* __restrict__ bout, const float* __restrict__ Win,
    const float* __restrict__ bin, float* __restrict__ hs_out,
    float* __restrict__ hs_in)
{
    __shared__ float hsd[8 * H];
    const int n0 = blockIdx.x * 8;
    const int tid = threadIdx.x;
    const int e = tid >> 6, j = tid & 63;

    for (int idx = tid; idx < 8 * H; idx += 256) hsd[idx] = h[(size_t)n0 * H + idx];
    __syncthreads();

    float aO[8], aI[8];
    {
        const float bO = bout[e * H + j], bI = bin[e * H + j];
        #pragma unroll
        for (int nn = 0; nn < 8; ++nn) { aO[nn] = bO; aI[nn] = bI; }
    }
    for (int k = 0; k < H; ++k) {
        const float wo = Wout[(e * H + k) * H + j];
        const float wi = Win[(e * H + k) * H + j];
        #pragma unroll
        for (int nn = 0; nn < 8; ++nn) {
            const float hv = hsd[nn * H + k];
            aO[nn] += hv * wo;
            aI[nn] += hv * wi;
        }
    }
    #pragma unroll
    for (int nn = 0; nn < 8; ++nn) {
        hs_out[((size_t)e * N + n0 + nn) * H + j] = tanhf(aO[nn]);
        hs_in[((size_t)e * N + n0 + nn) * H + j]  = tanhf(aI[nn]);
    }
}

// ---------------------------------------------------------------------------
// K3: sparse message aggregation. One block per node, 8 waves: (dir,e) per wave.
// Within a wave: 16 lanes x float4 = one 256B row; 4 row-groups in parallel,
// unroll 2 -> 8 rows in flight per wave. Cross-group combine via shfl_xor.
// ---------------------------------------------------------------------------
__global__ __launch_bounds__(512) void k_msg(
    const float* __restrict__ hs_out, const float* __restrict__ hs_in,
    const int* __restrict__ cnt_out, const int* __restrict__ cnt_in,
    const unsigned short* __restrict__ idx_out, const unsigned short* __restrict__ idx_in,
    float* __restrict__ msg)
{
    const int n = blockIdx.x;
    const int tid = threadIdx.x;
    const int wv = tid >> 6;             // 0..7
    const int dir = wv >> 2;             // 0=out, 1=in
    const int e = wv & 3;
    const int lane = tid & 63;
    const int g = lane >> 4;             // row-group 0..3
    const int l = lane & 15;             // float4 column within row

    const float4* hs4 = (const float4*)((dir ? hs_in : hs_out) + (size_t)e * N * H);
    const int* cnt = dir ? cnt_in : cnt_out;
    const unsigned short* idx = dir ? idx_in : idx_out;

    const int r = e * N + n;
    const int c = min(cnt[r], CAP);
    const unsigned short* lst = idx + (size_t)r * CAP;

    float ax = 0.f, ay = 0.f, az = 0.f, aw = 0.f;
    int i = g;
    for (; i + 4 < c; i += 8) {
        const int m0 = lst[i];
        const int m1 = lst[i + 4];
        const float4 v0 = hs4[(size_t)m0 * (H / 4) + l];
        const float4 v1 = hs4[(size_t)m1 * (H / 4) + l];
        ax += v0.x + v1.x;
        ay += v0.y + v1.y;
        az += v0.z + v1.z;
        aw += v0.w + v1.w;
    }
    for (; i < c; i += 4) {
        const float4 v = hs4[(size_t)lst[i] * (H / 4) + l];
        ax += v.x; ay += v.y; az += v.z; aw += v.w;
    }

    // combine the 4 row-groups (xor 16 then 32)
    ax += __shfl_xor(ax, 16, 64); ay += __shfl_xor(ay, 16, 64);
    az += __shfl_xor(az, 16, 64); aw += __shfl_xor(aw, 16, 64);
    ax += __shfl_xor(ax, 32, 64); ay += __shfl_xor(ay, 32, 64);
    az += __shfl_xor(az, 32, 64); aw += __shfl_xor(aw, 32, 64);

    if (g == 0) {
        float4* mdst = (float4*)msg;
        mdst[(size_t)n * (MSGW / 4) + dir * (E * H / 4) + e * (H / 4) + l] =
            make_float4(ax, ay, az, aw);
    }
}

// ---------------------------------------------------------------------------
// K4: fused GRU + 4 LayerNorms. 8 nodes per 256-thread block (2 nodes/wave).
// ---------------------------------------------------------------------------
__global__ __launch_bounds__(256) void k_gru(
    const float* __restrict__ msg, const float* __restrict__ h,
    const float* __restrict__ Wih_rz, const float* __restrict__ bih_rz,
    const float* __restrict__ Whh_rz, const float* __restrict__ bhh_rz,
    const float* __restrict__ Wih_c, const float* __restrict__ bih_c,
    const float* __restrict__ Whh_c, const float* __restrict__ bhh_c,
    const float* __restrict__ g_i2h, const float* __restrict__ be_i2h,
    const float* __restrict__ g_h2h, const float* __restrict__ be_h2h,
    const float* __restrict__ g_ci, const float* __restrict__ be_ci,
    const float* __restrict__ g_ch, const float* __restrict__ be_ch,
    float* __restrict__ h_out)
{
    __shared__ float ms[8 * MSGW];   // 16 KB
    __shared__ float hsd[8 * H];     // 2 KB
    const int n0 = blockIdx.x * 8;
    const int tid = threadIdx.x;
    const int j = tid & 63;
    const int wv = tid >> 6;         // 0..3
    const int nn0 = wv * 2;          // this wave owns nodes nn0, nn0+1

    {   // stage msg + h
        const float4* msrc = (const float4*)(msg + (size_t)n0 * MSGW);
        float4* mdst = (float4*)ms;
        for (int idx = tid; idx < 8 * MSGW / 4; idx += 256) mdst[idx] = msrc[idx];
        const float4* hsrc = (const float4*)(h + (size_t)n0 * H);
        float4* hdst = (float4*)hsd;
        for (int idx = tid; idx < 8 * H / 4; idx += 256) hdst[idx] = hsrc[idx];
    }
    __syncthreads();

    // x_rz = msg @ W_ih_rz + b   (thread j holds cols j, j+64, 2 nodes)
    float a0[2], a1[2], b0[2], b1[2];
    {
        const float v0 = bih_rz[j], v1 = bih_rz[H + j];
        #pragma unroll
        for (int nn = 0; nn < 2; ++nn) { a0[nn] = v0; a1[nn] = v1; }
    }
    for (int k = 0; k < MSGW; ++k) {
        const float w0 = Wih_rz[k * GH + j];
        const float w1 = Wih_rz[k * GH + H + j];
        #pragma unroll
        for (int nn = 0; nn < 2; ++nn) {
            const float mv = ms[(nn0 + nn) * MSGW + k];
            a0[nn] += mv * w0;
            a1[nn] += mv * w1;
        }
    }
    {
        const float v0 = bhh_rz[j], v1 = bhh_rz[H + j];
        #pragma unroll
        for (int nn = 0; nn < 2; ++nn) { b0[nn] = v0; b1[nn] = v1; }
    }
    for (int k = 0; k < H; ++k) {
        const float w0 = Whh_rz[k * GH + j];
        const float w1 = Whh_rz[k * GH + H + j];
        #pragma unroll
        for (int nn = 0; nn < 2; ++nn) {
            const float hv = hsd[(nn0 + nn) * H + k];
            b0[nn] += hv * w0;
            b1[nn] += hv * w1;
        }
    }

    const float gi0 = g_i2h[j], gi1 = g_i2h[H + j], bi0 = be_i2h[j], bi1 = be_i2h[H + j];
    const float gh0 = g_h2h[j], gh1 = g_h2h[H + j], bh0 = be_h2h[j], bh1 = be_h2h[H + j];
    float r_[2], z_[2];
    #pragma unroll
    for (int nn = 0; nn < 2; ++nn) {
        float s  = wsum(a0[nn] + a1[nn]);
        float q  = wsum(a0[nn] * a0[nn] + a1[nn] * a1[nn]);
        float mn = s * (1.f / GH);
        float vr = q * (1.f / GH) - mn * mn;
        float rs = rsqrtf(vr + 1e-5f);
        float x0 = (a0[nn] - mn) * rs * gi0 + bi0;
        float x1 = (a1[nn] - mn) * rs * gi1 + bi1;
        float s2  = wsum(b0[nn] + b1[nn]);
        float q2  = wsum(b0[nn] * b0[nn] + b1[nn] * b1[nn]);
        float mn2 = s2 * (1.f / GH);
        float vr2 = q2 * (1.f / GH) - mn2 * mn2;
        float rs2 = rsqrtf(vr2 + 1e-5f);
        float y0 = (b0[nn] - mn2) * rs2 * gh0 + bh0;
        float y1 = (b1[nn] - mn2) * rs2 * gh1 + bh1;
        r_[nn] = 1.f / (1.f + expf(-(x0 + y0)));
        z_[nn] = 1.f / (1.f + expf(-(x1 + y1)));
    }

    // x_c = msg @ W_ih_c, hn_c = h @ W_hh_c
    float c0[2], ch[2];
    {
        const float v = bih_c[j];
        #pragma unroll
        for (int nn = 0; nn < 2; ++nn) c0[nn] = v;
    }
    for (int k = 0; k < MSGW; ++k) {
        const float w = Wih_c[k * H + j];
        #pragma unroll
        for (int nn = 0; nn < 2; ++nn) c0[nn] += ms[(nn0 + nn) * MSGW + k] * w;
    }
    {
        const float v = bhh_c[j];
        #pragma unroll
        for (int nn = 0; nn < 2; ++nn) ch[nn] = v;
    }
    for (int k = 0; k < H; ++k) {
        const float w = Whh_c[k * H + j];
        #pragma unroll
        for (int nn = 0; nn < 2; ++nn) ch[nn] += hsd[(nn0 + nn) * H + k] * w;
    }

    const float gci = g_ci[j], bci = be_ci[j], gchv = g_ch[j], bchv = be_ch[j];
    #pragma unroll
    for (int nn = 0; nn < 2; ++nn) {
        float s  = wsum(c0[nn]);
        float q  = wsum(c0[nn] * c0[nn]);
        float mn = s * (1.f / H);
        float vr = q * (1.f / H) - mn * mn;
        float rs = rsqrtf(vr + 1e-5f);
        float xc = (c0[nn] - mn) * rs * gci + bci;
        float s2  = wsum(ch[nn]);
        float q2  = wsum(ch[nn] * ch[nn]);
        float mn2 = s2 * (1.f / H);
        float vr2 = q2 * (1.f / H) - mn2 * mn2;
        float rs2 = rsqrtf(vr2 + 1e-5f);
        float hc = (ch[nn] - mn2) * rs2 * gchv + bchv;
        float c  = tanhf(xc + r_[nn] * hc);
        const float hp = hsd[(nn0 + nn) * H + j];
        h_out[(size_t)(n0 + nn0 + nn) * H + j] = z_[nn] * hp + (1.f - z_[nn]) * c;
    }
}

// ---------------------------------------------------------------------------
extern "C" void kernel_launch(void* const* d_in, const int* in_sizes, int n_in,
                              void* d_out, int out_size, void* d_ws, size_t ws_size,
                              hipStream_t stream)
{
    const float* A      = (const float*)d_in[0];
    const float* nstate = (const float*)d_in[1];
    // d_in[2] node_ids unused
    const float* nvec   = (const float*)d_in[3];
    const float* nsp    = (const float*)d_in[4];
    const float* Wred   = (const float*)d_in[5];
    const float* bred   = (const float*)d_in[6];
    const float* Winit  = (const float*)d_in[7];
    const float* binit  = (const float*)d_in[8];
    const float* Wout   = (const float*)d_in[9];
    const float* bout   = (const float*)d_in[10];
    const float* Wine   = (const float*)d_in[11];
    const float* bine   = (const float*)d_in[12];
    const float* Wih_rz = (const float*)d_in[13];
    const float* bih_rz = (const float*)d_in[14];
    const float* Whh_rz = (const float*)d_in[15];
    const float* bhh_rz = (const float*)d_in[16];
    const float* Wih_c  = (const float*)d_in[17];
    const float* bih_c  = (const float*)d_in[18];
    const float* Whh_c  = (const float*)d_in[19];
    const float* bhh_c  = (const float*)d_in[20];
    const float* g_i2h  = (const float*)d_in[21];
    const float* be_i2h = (const float*)d_in[22];
    const float* g_h2h  = (const float*)d_in[23];
    const float* be_h2h = (const float*)d_in[24];
    const float* g_ci   = (const float*)d_in[25];
    const float* be_ci  = (const float*)d_in[26];
    const float* g_ch   = (const float*)d_in[27];
    const float* be_ch  = (const float*)d_in[28];

    char* ws = (char*)d_ws;
    size_t off = 0;
    auto alloc = [&](size_t bytes) {
        void* p = ws + off;
        off += (bytes + 255) & ~(size_t)255;
        return p;
    };
    float* h0  = (float*)alloc((size_t)N * H * 4);
    float* h1  = (float*)alloc((size_t)N * H * 4);
    float* hsO = (float*)alloc((size_t)E * N * H * 4);
    float* hsI = (float*)alloc((size_t)E * N * H * 4);
    float* msg = (float*)alloc((size_t)N * MSGW * 4);
    int* cnts  = (int*)alloc((size_t)2 * E * N * 4);
    int* cnt_out = cnts;
    int* cnt_in  = cnts + E * N;
    unsigned short* idxO = (unsigned short*)alloc((size_t)E * N * CAP * 2);
    unsigned short* idxI = (unsigned short*)alloc((size_t)E * N * CAP * 2);

    k_zero<<<(2 * E * N / 4 + 255) / 256, 256, 0, stream>>>((int4*)cnts);
    k_init<<<N / 4, 64, 0, stream>>>(nvec, nstate, nsp, Wred, bred, Winit, binit, h0);
    k_build<<<E * N, 256, 0, stream>>>(A, cnt_out, cnt_in, idxO, idxI);

    const float* hc = h0;
    for (int t = 0; t < 2; ++t) {
        k_hs<<<N / 8, 256, 0, stream>>>(hc, Wout, bout, Wine, bine, hsO, hsI);
        k_msg<<<N, 512, 0, stream>>>(hsO, hsI, cnt_out, cnt_in, idxO, idxI, msg);
        float* hn = (t == 1) ? (float*)d_out : h1;
        k_gru<<<N / 8, 256, 0, stream>>>(msg, hc, Wih_rz, bih_rz, Whh_rz, bhh_rz,
                                         Wih_c, bih_c, Whh_c, bhh_c,
                                         g_i2h, be_i2h, g_h2h, be_h2h,
                                         g_ci, be_ci, g_ch, be_ch, hn);
        hc = hn;
    }
}